// Round 18
// baseline (103.125 us; speedup 1.0000x reference)
//
#include <hip/hip_runtime.h>
#include <hip/hip_bf16.h>
#include <stdint.h>

#define D_MODEL 1024
#define NHEAD   16
#define HEAD_DIM 64
#define BATCH   2
#define SEQ     2048
#define M_TOK   (BATCH*SEQ)     // 4096
#define N_QKV   (3*D_MODEL)     // 3072
#define KDIM    1024
// Q pre-scale folds softmax scale AND log2(e): softmax done in exp2 domain.
#define Q_SCALE (0.125f * 1.44269504088896f)

typedef __bf16 bf16_t;
typedef bf16_t bf16x8 __attribute__((ext_vector_type(8)));
typedef bf16_t bf16x4 __attribute__((ext_vector_type(4)));
typedef float  f32x4  __attribute__((ext_vector_type(4)));
typedef float  f32x16 __attribute__((ext_vector_type(16)));
typedef unsigned u32x4 __attribute__((ext_vector_type(4)));

// async global->LDS, 16B per lane. lds base must be wave-uniform; HW writes
// base + lane*16B.
__device__ __forceinline__ void gl_lds16(const void* g, void* l) {
    __builtin_amdgcn_global_load_lds(
        (__attribute__((address_space(1))) void*)(void*)(const_cast<void*>(g)),
        (__attribute__((address_space(3))) void*)l, 16, 0, 0);
}

// pack two f32 -> one u32 of 2 bf16 (RNE), gfx950
__device__ __forceinline__ unsigned cvtpk_bf16(float a, float b) {
    unsigned r;
    asm("v_cvt_pk_bf16_f32 %0, %1, %2" : "=v"(r) : "v"(a), "v"(b));
    return r;
}

// One fused fp32->bf16 convert for x (4096x1024), W_qkv (3072x1024),
// W_out (1024x1024): 2097152 float4s, exact grid.
#define N4_X  (M_TOK * KDIM / 4)
#define N4_W1 (N_QKV * KDIM / 4)
#define N4_W2 (D_MODEL * KDIM / 4)
__global__ void convert_all(const float* __restrict__ x,
                            const float* __restrict__ w1,
                            const float* __restrict__ w2,
                            bf16_t* __restrict__ ox,
                            bf16_t* __restrict__ o1,
                            bf16_t* __restrict__ o2) {
    int t = blockIdx.x * blockDim.x + threadIdx.x;
    const float* src;
    bf16_t* dst;
    int off;
    if (t < N4_X)                { src = x;  dst = ox; off = t; }
    else if (t < N4_X + N4_W1)   { src = w1; dst = o1; off = t - N4_X; }
    else                         { src = w2; dst = o2; off = t - N4_X - N4_W1; }
    float4 v = reinterpret_cast<const float4*>(src)[off];
    bf16x4 o = { (bf16_t)v.x, (bf16_t)v.y, (bf16_t)v.z, (bf16_t)v.w };
    reinterpret_cast<bf16x4*>(dst)[off] = o;
}

// C[m,n] = sum_k A[m,k]*B[n,k] (+bias). 128xTN tile, 4 waves (2x2:
// 64 rows x TN/2 cols each), BK=64, 16x16x32 bf16 MFMA. LDS rows 128B = 8
// chunks; T2 XOR-swizzle chunk^=row&7 (pre-swizzled source + swizzled
// ds_read). T1 XCD swizzle.
// MODE 0 (TN=64): qkv epilogue (bf16, Q scaled, V scattered transposed into
//   a kv-PERMUTED layout: within each 16-kv block, the middle two 4-groups
//   swap (t^12 iff bit2!=bit3) so attn's PV slot-map reads are single b128
//   chunks). TN=64 -> 1536 blocks = 6/CU (latency-bound kernel: block-level
//   overlap hides barrier drains; R14's gemm<1> 1->2 blocks/CU gave -33%).
// MODE 1 (TN=64):  fp32 out + bias; 512 blocks = 2/CU.
template <int MODE, int TN>
__global__ __launch_bounds__(256) void gemm_bt(
    const bf16_t* __restrict__ A,    // [M][1024]
    const bf16_t* __restrict__ Bw,   // [N][1024]
    const float*  __restrict__ bias, // [N]
    int N,
    bf16_t* __restrict__ qkv_out,    // MODE 0: [M][3072]
    bf16_t* __restrict__ vt_out,     // MODE 0: [B*H*64][2048], kv-permuted
    float*  __restrict__ f32_out)    // MODE 1: [M][N]
{
    constexpr int NJ = TN / 32;           // n-fragments per wave (4 or 2)
    __shared__ bf16_t As[128 * 64];
    __shared__ bf16_t Bs[TN * 64];

    // T1: XCD-aware bijective swizzle (gridDim %8 == 0 for both GEMMs)
    const int cpx = gridDim.x >> 3;
    const int bid = (blockIdx.x & 7) * cpx + (blockIdx.x >> 3);

    const int nbn = N / TN;
    const int bm = bid / nbn;
    const int bn = bid % nbn;
    const int m0 = bm * 128, n0 = bn * TN;
    const int tid = threadIdx.x, wave = tid >> 6, lane = tid & 63;
    const int wr = wave >> 1, wc = wave & 1;

    f32x4 acc[4][NJ] = {};

    // staging: lane -> row lane>>3 (of 8), chunk (lane&7)^row pre-swizzled,
    // so LDS[r][u] = G[r][u ^ (r&7)] with a linear LDS fill.
    const int srow = lane >> 3;
    const int scol = ((lane & 7) ^ srow) * 8;
    const bf16_t* gA0 = A  + (size_t)(m0 + wave * 32 + srow) * KDIM + scol;
    const bf16_t* gB0 = Bw + (size_t)(n0 + wave * (TN / 4) + srow) * KDIM + scol;
    bf16_t* lA0 = &As[(wave * 32) * 64];
    bf16_t* lB0 = &Bs[(wave * (TN / 4)) * 64];

    const int fr = lane & 15;
    const int kq = lane >> 4;

    for (int k0 = 0; k0 < KDIM; k0 += 64) {
#pragma unroll
        for (int c = 0; c < 4; c++)
            gl_lds16(gA0 + (size_t)(c * 8) * KDIM + k0, lA0 + (c * 8) * 64);
#pragma unroll
        for (int c = 0; c < TN / 32; c++)
            gl_lds16(gB0 + (size_t)(c * 8) * KDIM + k0, lB0 + (c * 8) * 64);
        __syncthreads();

        bf16x8 af[2][4], bfr[2][NJ];
#pragma unroll
        for (int kk = 0; kk < 2; kk++) {
            const int ch = (((kk << 2) | kq) ^ (fr & 7)) * 8;  // swizzled
#pragma unroll
            for (int i = 0; i < 4; i++)
                af[kk][i] = *reinterpret_cast<const bf16x8*>(
                    &As[(wr * 64 + i * 16 + fr) * 64 + ch]);
#pragma unroll
            for (int j = 0; j < NJ; j++)
                bfr[kk][j] = *reinterpret_cast<const bf16x8*>(
                    &Bs[(wc * (TN / 2) + j * 16 + fr) * 64 + ch]);
        }
        __builtin_amdgcn_s_setprio(1);
#pragma unroll
        for (int i = 0; i < 4; i++)
#pragma unroll
            for (int j = 0; j < NJ; j++) {
                acc[i][j] = __builtin_amdgcn_mfma_f32_16x16x32_bf16(
                    af[0][i], bfr[0][j], acc[i][j], 0, 0, 0);
                acc[i][j] = __builtin_amdgcn_mfma_f32_16x16x32_bf16(
                    af[1][i], bfr[1][j], acc[i][j], 0, 0, 0);
            }
        __builtin_amdgcn_s_setprio(0);
        __syncthreads();
    }

    // epilogue: C/D layout col=lane&15, row=(lane>>4)*4+reg  [verified m89/m91]
#pragma unroll
    for (int i = 0; i < 4; i++) {
#pragma unroll
        for (int j = 0; j < NJ; j++) {
            const int col = n0 + wc * (TN / 2) + j * 16 + fr;
            const float bv = bias[col];
            const int row0 = m0 + wr * 64 + i * 16 + kq * 4;
            if (MODE == 1) {
#pragma unroll
                for (int r = 0; r < 4; r++)
                    f32_out[(size_t)(row0 + r) * N + col] = acc[i][j][r] + bv;
            } else if (col < 1024) {          // Q region (uniform per block)
#pragma unroll
                for (int r = 0; r < 4; r++)
                    qkv_out[(size_t)(row0 + r) * N_QKV + col] =
                        (bf16_t)((acc[i][j][r] + bv) * Q_SCALE);
            } else if (col < 2048) {          // K region
#pragma unroll
                for (int r = 0; r < 4; r++)
                    qkv_out[(size_t)(row0 + r) * N_QKV + col] =
                        (bf16_t)(acc[i][j][r] + bv);
            } else {                          // V region: packed transpose,
                                              // kv-permuted (t^12 iff b2!=b3)
                const int d = col & 63, hh = (col >> 6) & 15;
                const int bb = row0 >> 11, t0 = row0 & 2047;
                const int t0p = t0 ^ ((((t0 >> 2) ^ (t0 >> 3)) & 1) ? 12 : 0);
                bf16x4 pv = { (bf16_t)(acc[i][j][0] + bv),
                              (bf16_t)(acc[i][j][1] + bv),
                              (bf16_t)(acc[i][j][2] + bv),
                              (bf16_t)(acc[i][j][3] + bv) };
                *reinterpret_cast<bf16x4*>(
                    &vt_out[((size_t)((bb * NHEAD + hh) * HEAD_DIM + d)) * SEQ + t0p]) = pv;
            }
        }
    }
}

// Flash attention, causal, exp2 domain, fixed-max softmax, in-block kv-split,
// 32x32x16 MFMA core, permutation-safe PV.
// MFMA pairs A-slot (g,e) with B-slot (g,e); both operands present the SAME
// kv per slot, chosen as P's natural in-register layout from the HW-verified
// C/D mapping (kv = 16c + 8*(e>>2) + 4g + (e&3), own-lane):
//   B (P): 4x v_cvt_pk_bf16_f32 over consecutive acc regs — no LDS.
//   A (V): vt is stored kv-PERMUTED (see gemm MODE 0), so each MFMA's 8
//          V-slots are ONE 16B chunk -> single ds_read_b128.
// 256 threads = 2 kv-groups x 2 q-waves (32 q-rows/wave). One K-frag read
// serves 32 q, P LDS roundtrip gone, LDS 32 KB. l per-lane, reduced once
// (xor 32). Combine across kv-groups via LDS overlay (pure addition).
__global__ __launch_bounds__(256, 4) void attn_fwd(
    const bf16_t* __restrict__ qkv,  // [4096][3072], Q pre-scaled (exp2 dom)
    const bf16_t* __restrict__ Vt,   // [(b*16+h)*64 + d][2048], kv-permuted
    bf16_t* __restrict__ O)          // [4096][1024]
{
    __shared__ bf16_t Ks[2][64 * 64];     // per-group [kv][d], chunk-swizzled
    __shared__ bf16_t Vs[2][64 * 64];     // per-group [d][kv-perm], swizzled

    const int nqt = SEQ / 64;             // 32
    const int nbh = BATCH * NHEAD;        // 32
    const int qt = (nqt - 1) - (blockIdx.x / nbh);  // LPT: long blocks first
    const int bh = blockIdx.x % nbh;
    const int b = bh >> 4, h = bh & 15;
    const int q0 = qt * 64;
    const int tid = threadIdx.x, wave = tid >> 6, lane = tid & 63;
    const int group = wave >> 1;          // kv-split half 0/1
    const int w4 = wave & 1;              // q sub-tile (32 rows)
    const int ln31 = lane & 31;           // q (B col) / frag row (A)
    const int ag = lane >> 5;             // slot group g
    const int akey = ln31 & 7;            // XOR-swizzle key (row&7)

    // Q fragments (B operand): col=q=ln31, slot (g,e) -> d = c*16 + 8g + e
    bf16x8 qf[4];
    {
        const size_t qrow = (size_t)(b * SEQ + q0 + w4 * 32 + ln31);
        const bf16_t* qp = qkv + qrow * N_QKV + h * 64 + ag * 8;
        qf[0] = *reinterpret_cast<const bf16x8*>(qp);
        qf[1] = *reinterpret_cast<const bf16x8*>(qp + 16);
        qf[2] = *reinterpret_cast<const bf16x8*>(qp + 32);
        qf[3] = *reinterpret_cast<const bf16x8*>(qp + 48);
    }

    // O^T accumulator: acc[dm][r] = O^T[d = dm*32+(r&3)+8*(r>>2)+4*ag][q=ln31]
    f32x16 acc[2] = {};
    float l_part = 0.f;

    // staging: lane -> row lane>>3 (of 8), source chunk pre-swizzled:
    // chunk = (lane&7) ^ row, so LDS[r][u] = G[r][u ^ (r&7)] (linear fill).
    const int srow = lane >> 3;
    const int scol = ((lane & 7) ^ srow) * 8;
    const bf16_t* gK = qkv + (size_t)(b * SEQ) * N_QKV + (D_MODEL + h * 64);
    const bf16_t* gV = Vt + (size_t)(bh * 64) * SEQ;

    // kv-split: group 0 -> tiles [0, nh0), group 1 -> [nh0, qt+1)
    const int nh0 = (qt + 2) >> 1;
    const int my_n = (group == 0) ? nh0 : (qt + 1 - nh0);
    const int base_t = (group == 0) ? 0 : nh0;

    for (int it = 0; it < nh0; ++it) {
        const bool act = (it < my_n);
        const int g_it = base_t + it;
        const int kv0 = g_it * 64;
        if (act) {
            // 2 waves of the group stage rows w4*32..+31 of K and Vt
#pragma unroll
            for (int c = 0; c < 4; c++) {
                const int row = w4 * 32 + c * 8 + srow;
                gl_lds16(gK + (size_t)(kv0 + row) * N_QKV + scol,
                         &Ks[group][(w4 * 32 + c * 8) * 64]);
                gl_lds16(gV + (size_t)row * SEQ + kv0 + scol,
                         &Vs[group][(w4 * 32 + c * 8) * 64]);
            }
        }
        __syncthreads();

        if (act) {
            // process the two 32-kv halves sequentially (caps VGPR)
#pragma unroll
            for (int m = 0; m < 2; m++) {
                // S^T = K Q^T : A=K rows kv=m*32+ln31, B=Q cols q=ln31
                f32x16 s = {};
                __builtin_amdgcn_s_setprio(1);
#pragma unroll
                for (int c = 0; c < 4; c++) {
                    bf16x8 kf = *reinterpret_cast<const bf16x8*>(
                        &Ks[group][(m * 32 + ln31) * 64 + (((c * 2 + ag) ^ akey) * 8)]);
                    s = __builtin_amdgcn_mfma_f32_32x32x16_bf16(kf, qf[c], s, 0, 0, 0);
                }
                __builtin_amdgcn_s_setprio(0);

                // causal mask (diagonal tile only); C/D row = kv [m74/m101]
                if (g_it == qt) {
                    const int qg = w4 * 32 + ln31;
#pragma unroll
                    for (int r = 0; r < 16; r++) {
                        const int kvl = m * 32 + (r & 3) + 8 * (r >> 2) + 4 * ag;
                        if (kvl > qg) s[r] = -1e30f;
                    }
                }

                // fixed-max softmax: P = exp2(S) (masked -> 0); l per-lane
                float rs = 0.f;
#pragma unroll
                for (int r = 0; r < 16; r++) {
                    const float p = exp2f(s[r]);
                    s[r] = p;
                    rs += p;
                }
                l_part += rs;

                // PV, chunks c2=0,1 (16 kv each). Slot map (own-lane):
                // (g,e) -> kv = 16c2 + 8*(e>>2) + 4g + (e&3); B regs are
                // consecutive s[8c2+0..7]; V is kv-PERMUTED in memory so the
                // matching 8 slots = LDS chunk (4m+2c2+g) -> one b128 read.
                __builtin_amdgcn_s_setprio(1);
#pragma unroll
                for (int c2 = 0; c2 < 2; c2++) {
                    const int bs = c2 * 8;
                    u32x4 bw = { cvtpk_bf16(s[bs + 0], s[bs + 1]),
                                 cvtpk_bf16(s[bs + 2], s[bs + 3]),
                                 cvtpk_bf16(s[bs + 4], s[bs + 5]),
                                 cvtpk_bf16(s[bs + 6], s[bs + 7]) };
                    bf16x8 pb = __builtin_bit_cast(bf16x8, bw);
                    const int C = 4 * m + 2 * c2 + ag;
#pragma unroll
                    for (int dm = 0; dm < 2; dm++) {
                        bf16x8 vf = *reinterpret_cast<const bf16x8*>(
                            &Vs[group][(dm * 32 + ln31) * 64 + ((C ^ akey) * 8)]);
                        acc[dm] = __builtin_amdgcn_mfma_f32_32x32x16_bf16(
                            vf, pb, acc[dm], 0, 0, 0);
                    }
                }
                __builtin_amdgcn_s_setprio(0);
            }
        }
        __syncthreads();   // release K/V buffers for next tile
    }

    // ---- combine the two kv-halves (pure addition; fixed-max softmax) ----
    // Overlay f32 scratch on Ks/Vs (dead; fully barriered). Per w4:
    // 2048 acc floats (32 regs x 64 lanes) + 64 l floats.
    float* Cf = reinterpret_cast<float*>(&Ks[0][0]);
    const int cb = w4 * 2112;
    if (group == 1) {
#pragma unroll
        for (int dm = 0; dm < 2; dm++)
#pragma unroll
            for (int r = 0; r < 16; r++)
                Cf[cb + (dm * 16 + r) * 64 + lane] = acc[dm][r];
        Cf[cb + 2048 + lane] = l_part;
    }
    __syncthreads();
    if (group == 0) {
#pragma unroll
        for (int dm = 0; dm < 2; dm++)
#pragma unroll
            for (int r = 0; r < 16; r++)
                acc[dm][r] += Cf[cb + (dm * 16 + r) * 64 + lane];
        l_part += Cf[cb + 2048 + lane];

        // q-row replicas live on lane and lane^32 -> one shuffle
        l_part += __shfl_xor(l_part, 32);
        const float inv = 1.0f / l_part;
        const size_t rowq = (size_t)(b * SEQ + q0 + w4 * 32 + ln31);
#pragma unroll
        for (int dm = 0; dm < 2; dm++)
#pragma unroll
            for (int k = 0; k < 4; k++) {
                const int d0 = dm * 32 + 8 * k + 4 * ag;
                bf16x4 ov = { (bf16_t)(acc[dm][4 * k + 0] * inv),
                              (bf16_t)(acc[dm][4 * k + 1] * inv),
                              (bf16_t)(acc[dm][4 * k + 2] * inv),
                              (bf16_t)(acc[dm][4 * k + 3] * inv) };
                *reinterpret_cast<bf16x4*>(&O[rowq * D_MODEL + h * 64 + d0]) = ov;
            }
    }
}

extern "C" void kernel_launch(void* const* d_in, const int* in_sizes, int n_in,
                              void* d_out, int out_size, void* d_ws, size_t ws_size,
                              hipStream_t stream) {
    (void)in_sizes; (void)n_in; (void)out_size; (void)ws_size;
    const float* x    = (const float*)d_in[0];
    const float* Wqkv = (const float*)d_in[1];
    const float* bqkv = (const float*)d_in[2];
    const float* Wout = (const float*)d_in[3];
    const float* bout = (const float*)d_in[4];
    float* out = (float*)d_out;

    char* ws = (char*)d_ws;
    size_t off = 0;
    bf16_t* x_bf    = (bf16_t*)(ws + off); off += (size_t)M_TOK * KDIM * 2;        // 8 MB
    bf16_t* wqkv_bf = (bf16_t*)(ws + off); off += (size_t)N_QKV * KDIM * 2;        // 6 MB
    bf16_t* wout_bf = (bf16_t*)(ws + off); off += (size_t)D_MODEL * KDIM * 2;      // 2 MB
    bf16_t* qkv     = (bf16_t*)(ws + off); off += (size_t)M_TOK * N_QKV * 2;       // 24 MB
    bf16_t* vt      = (bf16_t*)(ws + off); off += (size_t)BATCH * NHEAD * HEAD_DIM * SEQ * 2; // 8 MB
    bf16_t* o_bf    = (bf16_t*)(ws + off); off += (size_t)M_TOK * D_MODEL * 2;     // 8 MB

    // one fused fp32 -> bf16 convert (exact grid: 2097152 float4s)
    convert_all<<<(N4_X + N4_W1 + N4_W2) / 256, 256, 0, stream>>>(
        x, Wqkv, Wout, x_bf, wqkv_bf, wout_bf);

    // QKV projection: [4096][3072], 128x64 tiles (1536 blocks, 6/CU)
    gemm_bt<0, 64><<<(M_TOK / 128) * (N_QKV / 64), 256, 0, stream>>>(
        x_bf, wqkv_bf, bqkv, N_QKV, qkv, vt, nullptr);

    // causal flash attention: 1024 blocks x 256 threads
    // (32x32 MFMA core, permuted-V b128 PV, in-block kv-split), LPT order
    attn_fwd<<<BATCH * NHEAD * (SEQ / 64), 256, 0, stream>>>(qkv, vt, o_bf);

    // output projection: fp32 out, 128x64 tiles (512 blocks, 2/CU)
    gemm_bt<1, 64><<<(M_TOK / 128) * (D_MODEL / 64), 256, 0, stream>>>(
        o_bf, wout_bf, bout, D_MODEL, nullptr, nullptr, out);
}

// Round 19
// 96.523 us; speedup vs baseline: 1.0684x; 1.0684x over previous
//
#include <hip/hip_runtime.h>
#include <hip/hip_bf16.h>
#include <stdint.h>

#define D_MODEL 1024
#define NHEAD   16
#define HEAD_DIM 64
#define BATCH   2
#define SEQ     2048
#define M_TOK   (BATCH*SEQ)     // 4096
#define N_QKV   (3*D_MODEL)     // 3072
#define KDIM    1024
// Q pre-scale folds softmax scale AND log2(e): softmax done in exp2 domain.
#define Q_SCALE (0.125f * 1.44269504088896f)

typedef __bf16 bf16_t;
typedef bf16_t bf16x8 __attribute__((ext_vector_type(8)));
typedef bf16_t bf16x4 __attribute__((ext_vector_type(4)));
typedef float  f32x4  __attribute__((ext_vector_type(4)));
typedef float  f32x16 __attribute__((ext_vector_type(16)));
typedef unsigned u32x4 __attribute__((ext_vector_type(4)));

// async global->LDS, 16B per lane. lds base must be wave-uniform; HW writes
// base + lane*16B.
__device__ __forceinline__ void gl_lds16(const void* g, void* l) {
    __builtin_amdgcn_global_load_lds(
        (__attribute__((address_space(1))) void*)(void*)(const_cast<void*>(g)),
        (__attribute__((address_space(3))) void*)l, 16, 0, 0);
}

// pack two f32 -> one u32 of 2 bf16 (RNE), gfx950
__device__ __forceinline__ unsigned cvtpk_bf16(float a, float b) {
    unsigned r;
    asm("v_cvt_pk_bf16_f32 %0, %1, %2" : "=v"(r) : "v"(a), "v"(b));
    return r;
}

// One fused fp32->bf16 convert for x (4096x1024), W_qkv (3072x1024),
// W_out (1024x1024): 2097152 float4s, exact grid.
#define N4_X  (M_TOK * KDIM / 4)
#define N4_W1 (N_QKV * KDIM / 4)
#define N4_W2 (D_MODEL * KDIM / 4)
__global__ void convert_all(const float* __restrict__ x,
                            const float* __restrict__ w1,
                            const float* __restrict__ w2,
                            bf16_t* __restrict__ ox,
                            bf16_t* __restrict__ o1,
                            bf16_t* __restrict__ o2) {
    int t = blockIdx.x * blockDim.x + threadIdx.x;
    const float* src;
    bf16_t* dst;
    int off;
    if (t < N4_X)                { src = x;  dst = ox; off = t; }
    else if (t < N4_X + N4_W1)   { src = w1; dst = o1; off = t - N4_X; }
    else                         { src = w2; dst = o2; off = t - N4_X - N4_W1; }
    float4 v = reinterpret_cast<const float4*>(src)[off];
    bf16x4 o = { (bf16_t)v.x, (bf16_t)v.y, (bf16_t)v.z, (bf16_t)v.w };
    reinterpret_cast<bf16x4*>(dst)[off] = o;
}

// C[m,n] = sum_k A[m,k]*B[n,k] (+bias). 128xTN tile, 4 waves (2x2:
// 64 rows x TN/2 cols each), BK=64, 16x16x32 bf16 MFMA. LDS rows 128B = 8
// chunks; T2 XOR-swizzle chunk^=row&7 (pre-swizzled source + swizzled
// ds_read). T1 XCD swizzle.
// MODE 0 (TN=128): qkv epilogue (bf16, Q scaled, V scattered transposed into
//   a kv-PERMUTED layout: within each 16-kv block, the middle two 4-groups
//   swap (t^12 iff bit2!=bit3) so attn's PV slot-map reads are single b128
//   chunks). TN=128 kept: R18 showed TN=64 halves MFMA-per-barrier and
//   regresses despite higher occupancy.
// MODE 1 (TN=64):  fp32 out + bias; 512 blocks = 2/CU (R14: +33%).
template <int MODE, int TN>
__global__ __launch_bounds__(256) void gemm_bt(
    const bf16_t* __restrict__ A,    // [M][1024]
    const bf16_t* __restrict__ Bw,   // [N][1024]
    const float*  __restrict__ bias, // [N]
    int N,
    bf16_t* __restrict__ qkv_out,    // MODE 0: [M][3072]
    bf16_t* __restrict__ vt_out,     // MODE 0: [B*H*64][2048], kv-permuted
    float*  __restrict__ f32_out)    // MODE 1: [M][N]
{
    constexpr int NJ = TN / 32;           // n-fragments per wave (4 or 2)
    __shared__ bf16_t As[128 * 64];
    __shared__ bf16_t Bs[TN * 64];

    // T1: XCD-aware bijective swizzle (gridDim %8 == 0 for both GEMMs)
    const int cpx = gridDim.x >> 3;
    const int bid = (blockIdx.x & 7) * cpx + (blockIdx.x >> 3);

    const int nbn = N / TN;
    const int bm = bid / nbn;
    const int bn = bid % nbn;
    const int m0 = bm * 128, n0 = bn * TN;
    const int tid = threadIdx.x, wave = tid >> 6, lane = tid & 63;
    const int wr = wave >> 1, wc = wave & 1;

    f32x4 acc[4][NJ] = {};

    // staging: lane -> row lane>>3 (of 8), chunk (lane&7)^row pre-swizzled,
    // so LDS[r][u] = G[r][u ^ (r&7)] with a linear LDS fill.
    const int srow = lane >> 3;
    const int scol = ((lane & 7) ^ srow) * 8;
    const bf16_t* gA0 = A  + (size_t)(m0 + wave * 32 + srow) * KDIM + scol;
    const bf16_t* gB0 = Bw + (size_t)(n0 + wave * (TN / 4) + srow) * KDIM + scol;
    bf16_t* lA0 = &As[(wave * 32) * 64];
    bf16_t* lB0 = &Bs[(wave * (TN / 4)) * 64];

    const int fr = lane & 15;
    const int kq = lane >> 4;

    for (int k0 = 0; k0 < KDIM; k0 += 64) {
#pragma unroll
        for (int c = 0; c < 4; c++)
            gl_lds16(gA0 + (size_t)(c * 8) * KDIM + k0, lA0 + (c * 8) * 64);
#pragma unroll
        for (int c = 0; c < TN / 32; c++)
            gl_lds16(gB0 + (size_t)(c * 8) * KDIM + k0, lB0 + (c * 8) * 64);
        __syncthreads();

        bf16x8 af[2][4], bfr[2][NJ];
#pragma unroll
        for (int kk = 0; kk < 2; kk++) {
            const int ch = (((kk << 2) | kq) ^ (fr & 7)) * 8;  // swizzled
#pragma unroll
            for (int i = 0; i < 4; i++)
                af[kk][i] = *reinterpret_cast<const bf16x8*>(
                    &As[(wr * 64 + i * 16 + fr) * 64 + ch]);
#pragma unroll
            for (int j = 0; j < NJ; j++)
                bfr[kk][j] = *reinterpret_cast<const bf16x8*>(
                    &Bs[(wc * (TN / 2) + j * 16 + fr) * 64 + ch]);
        }
        __builtin_amdgcn_s_setprio(1);
#pragma unroll
        for (int i = 0; i < 4; i++)
#pragma unroll
            for (int j = 0; j < NJ; j++) {
                acc[i][j] = __builtin_amdgcn_mfma_f32_16x16x32_bf16(
                    af[0][i], bfr[0][j], acc[i][j], 0, 0, 0);
                acc[i][j] = __builtin_amdgcn_mfma_f32_16x16x32_bf16(
                    af[1][i], bfr[1][j], acc[i][j], 0, 0, 0);
            }
        __builtin_amdgcn_s_setprio(0);
        __syncthreads();
    }

    // epilogue: C/D layout col=lane&15, row=(lane>>4)*4+reg  [verified m89/m91]
#pragma unroll
    for (int i = 0; i < 4; i++) {
#pragma unroll
        for (int j = 0; j < NJ; j++) {
            const int col = n0 + wc * (TN / 2) + j * 16 + fr;
            const float bv = bias[col];
            const int row0 = m0 + wr * 64 + i * 16 + kq * 4;
            if (MODE == 1) {
#pragma unroll
                for (int r = 0; r < 4; r++)
                    f32_out[(size_t)(row0 + r) * N + col] = acc[i][j][r] + bv;
            } else if (col < 1024) {          // Q region
#pragma unroll
                for (int r = 0; r < 4; r++)
                    qkv_out[(size_t)(row0 + r) * N_QKV + col] =
                        (bf16_t)((acc[i][j][r] + bv) * Q_SCALE);
            } else if (col < 2048) {          // K region
#pragma unroll
                for (int r = 0; r < 4; r++)
                    qkv_out[(size_t)(row0 + r) * N_QKV + col] =
                        (bf16_t)(acc[i][j][r] + bv);
            } else {                          // V region: packed transpose,
                                              // kv-permuted (t^12 iff b2!=b3)
                const int d = col & 63, hh = (col >> 6) & 15;
                const int bb = row0 >> 11, t0 = row0 & 2047;
                const int t0p = t0 ^ ((((t0 >> 2) ^ (t0 >> 3)) & 1) ? 12 : 0);
                bf16x4 pv = { (bf16_t)(acc[i][j][0] + bv),
                              (bf16_t)(acc[i][j][1] + bv),
                              (bf16_t)(acc[i][j][2] + bv),
                              (bf16_t)(acc[i][j][3] + bv) };
                *reinterpret_cast<bf16x4*>(
                    &vt_out[((size_t)((bb * NHEAD + hh) * HEAD_DIM + d)) * SEQ + t0p]) = pv;
            }
        }
    }
}

// Flash attention, causal, exp2 domain, fixed-max softmax, in-block kv-split,
// 32x32x16 MFMA core, permutation-safe PV (R17 version — best measured).
// MFMA pairs A-slot (g,e) with B-slot (g,e); both operands present the SAME
// kv per slot, chosen as P's natural in-register layout from the HW-verified
// C/D mapping (kv = 16c + 8*(e>>2) + 4g + (e&3), own-lane):
//   B (P): 4x v_cvt_pk_bf16_f32 over consecutive acc regs — no LDS.
//   A (V): vt is stored kv-PERMUTED (see gemm MODE 0), so each MFMA's 8
//          V-slots are ONE 16B chunk -> single ds_read_b128.
// 256 threads = 2 kv-groups x 2 q-waves (32 q-rows/wave). One K-frag read
// serves 32 q, P LDS roundtrip gone, LDS 32 KB. l per-lane, reduced once
// (xor 32). Combine across kv-groups via LDS overlay (pure addition).
__global__ __launch_bounds__(256, 4) void attn_fwd(
    const bf16_t* __restrict__ qkv,  // [4096][3072], Q pre-scaled (exp2 dom)
    const bf16_t* __restrict__ Vt,   // [(b*16+h)*64 + d][2048], kv-permuted
    bf16_t* __restrict__ O)          // [4096][1024]
{
    __shared__ bf16_t Ks[2][64 * 64];     // per-group [kv][d], chunk-swizzled
    __shared__ bf16_t Vs[2][64 * 64];     // per-group [d][kv-perm], swizzled

    const int nqt = SEQ / 64;             // 32
    const int nbh = BATCH * NHEAD;        // 32
    const int qt = (nqt - 1) - (blockIdx.x / nbh);  // LPT: long blocks first
    const int bh = blockIdx.x % nbh;
    const int b = bh >> 4, h = bh & 15;
    const int q0 = qt * 64;
    const int tid = threadIdx.x, wave = tid >> 6, lane = tid & 63;
    const int group = wave >> 1;          // kv-split half 0/1
    const int w4 = wave & 1;              // q sub-tile (32 rows)
    const int ln31 = lane & 31;           // q (B col) / frag row (A)
    const int ag = lane >> 5;             // slot group g
    const int akey = ln31 & 7;            // XOR-swizzle key (row&7)

    // Q fragments (B operand): col=q=ln31, slot (g,e) -> d = c*16 + 8g + e
    bf16x8 qf[4];
    {
        const size_t qrow = (size_t)(b * SEQ + q0 + w4 * 32 + ln31);
        const bf16_t* qp = qkv + qrow * N_QKV + h * 64 + ag * 8;
        qf[0] = *reinterpret_cast<const bf16x8*>(qp);
        qf[1] = *reinterpret_cast<const bf16x8*>(qp + 16);
        qf[2] = *reinterpret_cast<const bf16x8*>(qp + 32);
        qf[3] = *reinterpret_cast<const bf16x8*>(qp + 48);
    }

    // O^T accumulator: acc[dm][r] = O^T[d = dm*32+(r&3)+8*(r>>2)+4*ag][q=ln31]
    f32x16 acc[2] = {};
    float l_part = 0.f;

    // staging: lane -> row lane>>3 (of 8), source chunk pre-swizzled:
    // chunk = (lane&7) ^ row, so LDS[r][u] = G[r][u ^ (r&7)] (linear fill).
    const int srow = lane >> 3;
    const int scol = ((lane & 7) ^ srow) * 8;
    const bf16_t* gK = qkv + (size_t)(b * SEQ) * N_QKV + (D_MODEL + h * 64);
    const bf16_t* gV = Vt + (size_t)(bh * 64) * SEQ;

    // kv-split: group 0 -> tiles [0, nh0), group 1 -> [nh0, qt+1)
    const int nh0 = (qt + 2) >> 1;
    const int my_n = (group == 0) ? nh0 : (qt + 1 - nh0);
    const int base_t = (group == 0) ? 0 : nh0;

    for (int it = 0; it < nh0; ++it) {
        const bool act = (it < my_n);
        const int g_it = base_t + it;
        const int kv0 = g_it * 64;
        if (act) {
            // 2 waves of the group stage rows w4*32..+31 of K and Vt
#pragma unroll
            for (int c = 0; c < 4; c++) {
                const int row = w4 * 32 + c * 8 + srow;
                gl_lds16(gK + (size_t)(kv0 + row) * N_QKV + scol,
                         &Ks[group][(w4 * 32 + c * 8) * 64]);
                gl_lds16(gV + (size_t)row * SEQ + kv0 + scol,
                         &Vs[group][(w4 * 32 + c * 8) * 64]);
            }
        }
        __syncthreads();

        if (act) {
            // process the two 32-kv halves sequentially (caps VGPR)
#pragma unroll
            for (int m = 0; m < 2; m++) {
                // S^T = K Q^T : A=K rows kv=m*32+ln31, B=Q cols q=ln31
                f32x16 s = {};
                __builtin_amdgcn_s_setprio(1);
#pragma unroll
                for (int c = 0; c < 4; c++) {
                    bf16x8 kf = *reinterpret_cast<const bf16x8*>(
                        &Ks[group][(m * 32 + ln31) * 64 + (((c * 2 + ag) ^ akey) * 8)]);
                    s = __builtin_amdgcn_mfma_f32_32x32x16_bf16(kf, qf[c], s, 0, 0, 0);
                }
                __builtin_amdgcn_s_setprio(0);

                // causal mask (diagonal tile only); C/D row = kv [m74/m101]
                if (g_it == qt) {
                    const int qg = w4 * 32 + ln31;
#pragma unroll
                    for (int r = 0; r < 16; r++) {
                        const int kvl = m * 32 + (r & 3) + 8 * (r >> 2) + 4 * ag;
                        if (kvl > qg) s[r] = -1e30f;
                    }
                }

                // fixed-max softmax: P = exp2(S) (masked -> 0); l per-lane
                float rs = 0.f;
#pragma unroll
                for (int r = 0; r < 16; r++) {
                    const float p = exp2f(s[r]);
                    s[r] = p;
                    rs += p;
                }
                l_part += rs;

                // PV, chunks c2=0,1 (16 kv each). Slot map (own-lane):
                // (g,e) -> kv = 16c2 + 8*(e>>2) + 4g + (e&3); B regs are
                // consecutive s[8c2+0..7]; V is kv-PERMUTED in memory so the
                // matching 8 slots = LDS chunk (4m+2c2+g) -> one b128 read.
                __builtin_amdgcn_s_setprio(1);
#pragma unroll
                for (int c2 = 0; c2 < 2; c2++) {
                    const int bs = c2 * 8;
                    u32x4 bw = { cvtpk_bf16(s[bs + 0], s[bs + 1]),
                                 cvtpk_bf16(s[bs + 2], s[bs + 3]),
                                 cvtpk_bf16(s[bs + 4], s[bs + 5]),
                                 cvtpk_bf16(s[bs + 6], s[bs + 7]) };
                    bf16x8 pb = __builtin_bit_cast(bf16x8, bw);
                    const int C = 4 * m + 2 * c2 + ag;
#pragma unroll
                    for (int dm = 0; dm < 2; dm++) {
                        bf16x8 vf = *reinterpret_cast<const bf16x8*>(
                            &Vs[group][(dm * 32 + ln31) * 64 + ((C ^ akey) * 8)]);
                        acc[dm] = __builtin_amdgcn_mfma_f32_32x32x16_bf16(
                            vf, pb, acc[dm], 0, 0, 0);
                    }
                }
                __builtin_amdgcn_s_setprio(0);
            }
        }
        __syncthreads();   // release K/V buffers for next tile
    }

    // ---- combine the two kv-halves (pure addition; fixed-max softmax) ----
    // Overlay f32 scratch on Ks/Vs (dead; fully barriered). Per w4:
    // 2048 acc floats (32 regs x 64 lanes) + 64 l floats.
    float* Cf = reinterpret_cast<float*>(&Ks[0][0]);
    const int cb = w4 * 2112;
    if (group == 1) {
#pragma unroll
        for (int dm = 0; dm < 2; dm++)
#pragma unroll
            for (int r = 0; r < 16; r++)
                Cf[cb + (dm * 16 + r) * 64 + lane] = acc[dm][r];
        Cf[cb + 2048 + lane] = l_part;
    }
    __syncthreads();
    if (group == 0) {
#pragma unroll
        for (int dm = 0; dm < 2; dm++)
#pragma unroll
            for (int r = 0; r < 16; r++)
                acc[dm][r] += Cf[cb + (dm * 16 + r) * 64 + lane];
        l_part += Cf[cb + 2048 + lane];

        // q-row replicas live on lane and lane^32 -> one shuffle
        l_part += __shfl_xor(l_part, 32);
        const float inv = 1.0f / l_part;
        const size_t rowq = (size_t)(b * SEQ + q0 + w4 * 32 + ln31);
#pragma unroll
        for (int dm = 0; dm < 2; dm++)
#pragma unroll
            for (int k = 0; k < 4; k++) {
                const int d0 = dm * 32 + 8 * k + 4 * ag;
                bf16x4 ov = { (bf16_t)(acc[dm][4 * k + 0] * inv),
                              (bf16_t)(acc[dm][4 * k + 1] * inv),
                              (bf16_t)(acc[dm][4 * k + 2] * inv),
                              (bf16_t)(acc[dm][4 * k + 3] * inv) };
                *reinterpret_cast<bf16x4*>(&O[rowq * D_MODEL + h * 64 + d0]) = ov;
            }
    }
}

extern "C" void kernel_launch(void* const* d_in, const int* in_sizes, int n_in,
                              void* d_out, int out_size, void* d_ws, size_t ws_size,
                              hipStream_t stream) {
    (void)in_sizes; (void)n_in; (void)out_size; (void)ws_size;
    const float* x    = (const float*)d_in[0];
    const float* Wqkv = (const float*)d_in[1];
    const float* bqkv = (const float*)d_in[2];
    const float* Wout = (const float*)d_in[3];
    const float* bout = (const float*)d_in[4];
    float* out = (float*)d_out;

    char* ws = (char*)d_ws;
    size_t off = 0;
    bf16_t* x_bf    = (bf16_t*)(ws + off); off += (size_t)M_TOK * KDIM * 2;        // 8 MB
    bf16_t* wqkv_bf = (bf16_t*)(ws + off); off += (size_t)N_QKV * KDIM * 2;        // 6 MB
    bf16_t* wout_bf = (bf16_t*)(ws + off); off += (size_t)D_MODEL * KDIM * 2;      // 2 MB
    bf16_t* qkv     = (bf16_t*)(ws + off); off += (size_t)M_TOK * N_QKV * 2;       // 24 MB
    bf16_t* vt      = (bf16_t*)(ws + off); off += (size_t)BATCH * NHEAD * HEAD_DIM * SEQ * 2; // 8 MB
    bf16_t* o_bf    = (bf16_t*)(ws + off); off += (size_t)M_TOK * D_MODEL * 2;     // 8 MB

    // one fused fp32 -> bf16 convert (exact grid: 2097152 float4s)
    convert_all<<<(N4_X + N4_W1 + N4_W2) / 256, 256, 0, stream>>>(
        x, Wqkv, Wout, x_bf, wqkv_bf, wout_bf);

    // QKV projection: [4096][3072], 128x128 tiles (768 blocks, 3/CU)
    gemm_bt<0, 128><<<(M_TOK / 128) * (N_QKV / 128), 256, 0, stream>>>(
        x_bf, wqkv_bf, bqkv, N_QKV, qkv, vt, nullptr);

    // causal flash attention: 1024 blocks x 256 threads
    // (32x32 MFMA core, permuted-V b128 PV, in-block kv-split), LPT order
    attn_fwd<<<BATCH * NHEAD * (SEQ / 64), 256, 0, stream>>>(qkv, vt, o_bf);

    // output projection: fp32 out, 128x64 tiles (512 blocks, 2/CU)
    gemm_bt<1, 64><<<(M_TOK / 128) * (D_MODEL / 64), 256, 0, stream>>>(
        o_bf, wout_bf, bout, D_MODEL, nullptr, nullptr, out);
}